// Round 12
// baseline (482.677 us; speedup 1.0000x reference)
//
#include <hip/hip_runtime.h>
#include <math.h>

// ResBlock via bf16 MFMA implicit-GEMM conv3x3.
// R12: 32x32x16 MFMA, wave tile 128co x 64px -> 43.7 FLOP per LDS byte
// (R6/R9/R11 post-mortem: all ~230us variants shared 32 FLOP/B intensity;
// LDS pipe was the invariant limit, not the schedule). Block 256thr/4 waves,
// 256co x 128px, LDS 64KB (x dbuf + w dbuf), 2 blocks/CU, grid 1152.
// R11's staging protocol (per-region w slice, chunk-edge x, counted vmcnt,
// pre-swizzled gl_lds source per rule #21) kept verbatim.
// B=16, C=256, H=W=96. Padded channels-last bf16 intermediates [16][98][98][256].

#define Bn 16
#define Cn 256
#define Hn 96
#define Wn 96
#define PH 98
#define PW 98
#define HW (Hn*Wn)

typedef __bf16 bf16x8 __attribute__((ext_vector_type(8)));
typedef float  f32x16 __attribute__((ext_vector_type(16)));

__device__ __forceinline__ unsigned short f2bf(float f) {
    unsigned int u = __float_as_uint(f);
    unsigned int r = (u + 0x7fffu + ((u >> 16) & 1u)) >> 16;
    return (unsigned short)r;
}

__device__ __forceinline__ void lds_load16(void* lds, const void* g) {
    auto gp = (const __attribute__((address_space(1))) char*)(unsigned long long)(uintptr_t)g;
    auto lp = (__attribute__((address_space(3))) char*)(unsigned int)(uintptr_t)lds;
    __builtin_amdgcn_global_load_lds(gp, lp, 16, 0, 0);
}

#define SB() __builtin_amdgcn_sched_barrier(0)
#define MEMFENCE() asm volatile("" ::: "memory")

// ---- zero the padded border of a CL tensor ----
__global__ __launch_bounds__(256)
void zero_border_k(unsigned short* __restrict__ t) {
    int idx = blockIdx.x * 256 + threadIdx.x;      // 16*388*32 threads
    int oct = idx & 31;
    int rest = idx >> 5;
    int pidx = rest % 388;
    int b = rest / 388;
    int h, w;
    if (pidx < 98)       { h = 0;  w = pidx; }
    else if (pidx < 196) { h = 97; w = pidx - 98; }
    else if (pidx < 292) { h = pidx - 196 + 1; w = 0; }
    else                 { h = pidx - 292 + 1; w = 97; }
    size_t e = ((size_t)(b * PH + h) * PW + w) * 256 + oct * 8;
    *(uint4*)(t + e) = make_uint4(0u, 0u, 0u, 0u);
}

// ---- pack weights fp32 [co][ci][3][3] -> bf16 [cc][k9][c'][ci32] ----
template<bool PERM>
__global__ __launch_bounds__(256)
void pack_w_k(const float* __restrict__ w, unsigned short* __restrict__ wp) {
    int idx = blockIdx.x * 256 + threadIdx.x;      // 589824
    int ci_l = idx & 31;
    int c    = (idx >> 5) & 255;
    int v    = idx >> 13;          // 0..71
    int k9   = v % 9;
    int cc   = v / 9;
    int co;
    if (PERM) {
        co = (c < 86) ? c * 3 : (c < 171) ? (c - 86) * 3 + 1 : (c - 171) * 3 + 2;
    } else {
        co = c;
    }
    float val = w[((size_t)co * 256 + cc * 32 + ci_l) * 9 + k9];
    wp[idx] = f2bf(val);
}

// ---- x fp32 NCHW -> padded channels-last bf16 (interior only) ----
__global__ __launch_bounds__(256)
void transform_x_k(const float* __restrict__ x, unsigned short* __restrict__ xp) {
    __shared__ float s[32 * 33];
    const int t = threadIdx.x;
    const int col0 = blockIdx.x * 32;
    const int row  = blockIdx.y;
    const int z = blockIdx.z;
    const int b = z >> 3;
    const int ci0 = (z & 7) * 32;

    #pragma unroll
    for (int i = 0; i < 4; ++i) {
        int ci = i * 8 + (t >> 5);
        int px = t & 31;
        s[ci * 33 + px] = x[((size_t)(b * Cn + ci0 + ci)) * HW + row * Wn + col0 + px];
    }
    __syncthreads();
    const int px = t >> 3;
    const int c4 = (t & 7) * 4;
    ushort4 o;
    o.x = f2bf(s[(c4 + 0) * 33 + px]);
    o.y = f2bf(s[(c4 + 1) * 33 + px]);
    o.z = f2bf(s[(c4 + 2) * 33 + px]);
    o.w = f2bf(s[(c4 + 3) * 33 + px]);
    size_t e = ((size_t)(b * PH + row + 1) * PW + (col0 + px + 1)) * 256 + ci0 + c4;
    *(ushort4*)(xp + e) = o;
}

// ---- MFMA conv3x3, 32x32x16 shape ----
// 256 threads (4 waves). Block: 256 co x (4 rows x 32 cols = 128 px).
// Wave wv: co-half ch=wv&1 (128 co: m=4 frags of 32), row-pair ph=wv>>1
// (rows ph*2, ph*2+1: n=2 frags, each one 32-px row). K chunk ci32 = 2 k-frags.
// Per region s=(c*9+k9): 12 ds_read_b128 -> 16 mfma_32x32x16 per wave.
// s_w dbuf 2x16KB [co256][ci32] slice; s_x dbuf 2x16KB (6 rows x 34 cols halo).
// Staging via global_load_lds, PRE-SWIZZLED SOURCE (rule #21), involution
// phys16Bslot = logical ^ ((logical>>3)&3); reads apply the same XOR.
// Frag maps (gfx950): A/B lane: row|col=lane&31, K=(lane>>5)*8+e;
// C/D: col(px)=lane&31, row(co)=(reg&3)+8*(reg>>2)+4*(lane>>5).
template<int MODE>
__global__ __launch_bounds__(256, 2)
void conv_k(const unsigned short* __restrict__ in_cl,
            const unsigned short* __restrict__ wp,
            const float* __restrict__ prelu_w,
            const float* __restrict__ xres,
            void* __restrict__ outp)
{
    __shared__ unsigned short s_x[2][1024 * 8];   // 2 x 16384 B
    __shared__ unsigned short s_w[2][1024 * 8];   // 2 x 16384 B

    const int tid = threadIdx.x;
    const int bid = blockIdx.x;
    // XCD-chunked bijective swizzle (1152 = 8 * 144).
    const int wg = (bid & 7) * 144 + (bid >> 3);
    const int tile = wg % 72;
    const int b = wg / 72;
    const int R0 = (tile / 3) * 4;     // halo base row (padded coords)
    const int C0 = (tile % 3) * 32;

    const int lane = tid & 63;
    const int wv = tid >> 6;
    const int l31 = lane & 31;
    const int lh = lane >> 5;
    const int ch = wv & 1;             // co half (0/1 -> co base ch*128)
    const int ph = wv >> 1;            // row pair (rows ph*2, ph*2+1)
    const int swA = (l31 >> 1) & 3;

    const unsigned short* img = in_cl + (size_t)b * PH * PW * 256;

    // ---- staging maps (gl_lds dest linear = i*256+tid; source pre-swizzled) ----
    // x: 6 rows x 34 cols = 204 px * 4 parts = 816 logical slots; 4/thread
    int xg[4];
    #pragma unroll
    for (int i = 0; i < 4; ++i) {
        int slot = i * 256 + tid;
        int lsl = slot ^ ((slot >> 3) & 3);    // involution
        if (lsl > 815) lsl = 815;
        int p = lsl >> 2;
        int pr = p / 34, pc = p - pr * 34;
        xg[i] = ((R0 + pr) * PW + (C0 + pc)) * 256 + (lsl & 3) * 8;
    }
    // w slice: 256 co * 4 parts = 1024 slots; 4/thread
    int wgo[4];
    #pragma unroll
    for (int i = 0; i < 4; ++i) {
        int slot = i * 256 + tid;
        int lsl = slot ^ ((slot >> 3) & 3);    // stays in [0,1024)
        wgo[i] = (lsl >> 2) * 32 + (lsl & 3) * 8;
    }

    f32x16 acc[4][2];
    #pragma unroll
    for (int m = 0; m < 4; ++m)
        #pragma unroll
        for (int n = 0; n < 2; ++n) acc[m][n] = 0.f;

    // ---- prologue: w(0) -> s_w[0], x(0) -> s_x[0] ----
    #pragma unroll
    for (int i = 0; i < 4; ++i) lds_load16(&s_w[0][(size_t)(i * 256 + tid) * 8], wp + wgo[i]);
    #pragma unroll
    for (int i = 0; i < 4; ++i) lds_load16(&s_x[0][(size_t)(i * 256 + tid) * 8], img + xg[i]);
    MEMFENCE(); SB();
    asm volatile("s_waitcnt vmcnt(0)" ::: "memory");
    SB();
    __builtin_amdgcn_s_barrier();
    SB();

    for (int s = 0; s < 72; ++s) {
        const int c  = s / 9;
        const int k9 = s - 9 * c;
        const int kh = k9 / 3, kw = k9 - 3 * kh;
        const unsigned short* swc = s_w[s & 1];
        const unsigned short* sxc = s_x[c & 1];

        // ---- staging issues (w first, then x: per-wave FIFO for vmcnt) ----
        if (s < 71) {
            #pragma unroll
            for (int i = 0; i < 4; ++i)
                lds_load16(&s_w[(s + 1) & 1][(size_t)(i * 256 + tid) * 8],
                           wp + (size_t)(s + 1) * 8192 + wgo[i]);
            MEMFENCE(); SB();
        }
        if (k9 == 8 && c < 7) {
            #pragma unroll
            for (int i = 0; i < 4; ++i)
                lds_load16(&s_x[(c + 1) & 1][(size_t)(i * 256 + tid) * 8],
                           img + xg[i] + (c + 1) * 32);
            MEMFENCE(); SB();
        }
        if (k9 == 0 && c > 0) {
            // drain x(c) (issued last region, oldest in FIFO); w(s+1) keeps flying
            asm volatile("s_waitcnt vmcnt(4)" ::: "memory");
            SB();
        }

        // ---- 12 ds_read_b128 -> 16 MFMA32 (compiler schedules lgkmcnt) ----
        bf16x8 a0[4], a1[4], b0[2], b1[2];
        #pragma unroll
        for (int m = 0; m < 4; ++m) {
            const int row = ch * 128 + m * 32 + l31;
            a0[m] = *(const bf16x8*)&swc[(row * 4 + (lh ^ swA)) * 8];
            a1[m] = *(const bf16x8*)&swc[(row * 4 + ((2 + lh) ^ swA)) * 8];
        }
        #pragma unroll
        for (int n = 0; n < 2; ++n) {
            const int px = (ph * 2 + n + kh) * 34 + l31 + kw;
            const int swB = (px >> 1) & 3;
            b0[n] = *(const bf16x8*)&sxc[(px * 4 + (lh ^ swB)) * 8];
            b1[n] = *(const bf16x8*)&sxc[(px * 4 + ((2 + lh) ^ swB)) * 8];
        }
        __builtin_amdgcn_s_setprio(1);
        #pragma unroll
        for (int n = 0; n < 2; ++n)
            #pragma unroll
            for (int m = 0; m < 4; ++m)
                acc[m][n] = __builtin_amdgcn_mfma_f32_32x32x16_bf16(a0[m], b0[n], acc[m][n], 0, 0, 0);
        #pragma unroll
        for (int n = 0; n < 2; ++n)
            #pragma unroll
            for (int m = 0; m < 4; ++m)
                acc[m][n] = __builtin_amdgcn_mfma_f32_32x32x16_bf16(a1[m], b1[n], acc[m][n], 0, 0, 0);
        __builtin_amdgcn_s_setprio(0);
        SB();

        // ---- end-of-region drain ----
        if (k9 == 8 && c < 7) {
            asm volatile("s_waitcnt vmcnt(4)" ::: "memory");   // w drained, x flies
        } else if (s < 71) {
            asm volatile("s_waitcnt vmcnt(0)" ::: "memory");   // w(s+1) drained
        }
        SB();
        __builtin_amdgcn_s_barrier();
        SB();
    }

    // ---- epilogue ----
    if constexpr (MODE == 0) {
        const float pw = prelu_w[0];
        unsigned short* aout = (unsigned short*)outp;
        #pragma unroll
        for (int n = 0; n < 2; ++n) {
            const int prow = R0 + ph * 2 + n + 1;
            size_t pix = ((size_t)(b * PH + prow)) * PW + (C0 + l31 + 1);
            #pragma unroll
            for (int m = 0; m < 4; ++m) {
                const int chb = ch * 128 + m * 32;
                #pragma unroll
                for (int p = 0; p < 8; ++p) {
                    const int base = chb + (p & 1) * 2 + (p >> 1) * 8 + 4 * lh;
                    float v0 = acc[m][n][2 * p];
                    float v1 = acc[m][n][2 * p + 1];
                    float r0, r1;
                    {
                        const int c0_ = base;
                        if (c0_ < 86)       r0 = v0 >= 0.f ? v0 : pw * v0;
                        else if (c0_ < 171) r0 = fmaxf(v0, 0.f);
                        else { float e = __expf(2.f * v0); r0 = 1.f - 2.f / (e + 1.f); }
                        const int c1_ = base + 1;
                        if (c1_ < 86)       r1 = v1 >= 0.f ? v1 : pw * v1;
                        else if (c1_ < 171) r1 = fmaxf(v1, 0.f);
                        else { float e = __expf(2.f * v1); r1 = 1.f - 2.f / (e + 1.f); }
                    }
                    unsigned int u = (unsigned int)f2bf(r0) | ((unsigned int)f2bf(r1) << 16);
                    *(unsigned int*)(aout + pix * 256 + base) = u;
                }
            }
        }
    } else {
        float* fout = (float*)outp;
        #pragma unroll
        for (int n = 0; n < 2; ++n) {
            const int row = R0 + ph * 2 + n;
            const int col = C0 + l31;
            #pragma unroll
            for (int m = 0; m < 4; ++m) {
                const int chb = ch * 128 + m * 32;
                #pragma unroll
                for (int r = 0; r < 16; ++r) {
                    const int chn = chb + (r & 3) + 8 * (r >> 2) + 4 * lh;
                    size_t idx = ((size_t)(b * Cn + chn)) * HW + (size_t)row * Wn + col;
                    fout[idx] = acc[m][n][r] * 0.1f + xres[idx];
                }
            }
        }
    }
}

extern "C" void kernel_launch(void* const* d_in, const int* in_sizes, int n_in,
                              void* d_out, int out_size, void* d_ws, size_t ws_size,
                              hipStream_t stream) {
    const float* x  = (const float*)d_in[0];
    const float* w2 = (const float*)d_in[1];
    const float* w3 = (const float*)d_in[2];
    const float* pw = (const float*)d_in[3];
    float* out = (float*)d_out;
    char* ws = (char*)d_ws;

    // ws layout: a_cl (78,675,968 B) | wp2 (1,179,648 B) | wp3 (1,179,648 B)  = 81 MB
    unsigned short* a_cl = (unsigned short*)ws;
    unsigned short* wp2  = (unsigned short*)(ws + 78675968);
    unsigned short* wp3  = (unsigned short*)(ws + 78675968 + 1179648);
    // x_pad aliases d_out (78.7 MB <= 151 MB); dead before conv<1> writes d_out.
    unsigned short* x_pad = (unsigned short*)d_out;

    zero_border_k<<<776, 256, 0, stream>>>(x_pad);
    zero_border_k<<<776, 256, 0, stream>>>(a_cl);
    pack_w_k<true ><<<2304, 256, 0, stream>>>(w2, wp2);
    pack_w_k<false><<<2304, 256, 0, stream>>>(w3, wp3);
    transform_x_k<<<dim3(3, 96, 128), 256, 0, stream>>>(x, x_pad);

    conv_k<0><<<1152, 256, 0, stream>>>(x_pad, wp2, pw, nullptr, (void*)a_cl);
    conv_k<1><<<1152, 256, 0, stream>>>(a_cl, wp3, nullptr, x, (void*)out);
}

// Round 13
// 412.205 us; speedup vs baseline: 1.1710x; 1.1710x over previous
//
#include <hip/hip_runtime.h>
#include <math.h>

// ResBlock via bf16 MFMA implicit-GEMM conv3x3.
// R13: weights NEVER touch LDS - A-frags load global->VGPR directly (wp is
// packed in exact fragment order; per-lane dwordx4, coalesced, L2-resident).
// LDS serves only x (B-frags): per-region LDS ~0.5x MFMA -> waves stagger
// into MFMA while LDS drains (m201's regime). One barrier per ci-chunk only;
// A(s+1) prefetched each region with counted vmcnt(1) (A-first FIFO order);
// x staged one gl_lds slice per region into the other buffer.
// B=16, C=256, H=W=96. Padded channels-last bf16 intermediates [16][98][98][256].

#define Bn 16
#define Cn 256
#define Hn 96
#define Wn 96
#define PH 98
#define PW 98
#define HW (Hn*Wn)

typedef __bf16 bf16x8 __attribute__((ext_vector_type(8)));
typedef float  f32x4  __attribute__((ext_vector_type(4)));

__device__ __forceinline__ unsigned short f2bf(float f) {
    unsigned int u = __float_as_uint(f);
    unsigned int r = (u + 0x7fffu + ((u >> 16) & 1u)) >> 16;
    return (unsigned short)r;
}

__device__ __forceinline__ void lds_load16(void* lds, const void* g) {
    auto gp = (const __attribute__((address_space(1))) char*)(unsigned long long)(uintptr_t)g;
    auto lp = (__attribute__((address_space(3))) char*)(unsigned int)(uintptr_t)lds;
    __builtin_amdgcn_global_load_lds(gp, lp, 16, 0, 0);
}

#define SB() __builtin_amdgcn_sched_barrier(0)
#define MEMFENCE() asm volatile("" ::: "memory")

// ---- zero the padded border of a CL tensor ----
__global__ __launch_bounds__(256)
void zero_border_k(unsigned short* __restrict__ t) {
    int idx = blockIdx.x * 256 + threadIdx.x;      // 16*388*32 threads
    int oct = idx & 31;
    int rest = idx >> 5;
    int pidx = rest % 388;
    int b = rest / 388;
    int h, w;
    if (pidx < 98)       { h = 0;  w = pidx; }
    else if (pidx < 196) { h = 97; w = pidx - 98; }
    else if (pidx < 292) { h = pidx - 196 + 1; w = 0; }
    else                 { h = pidx - 292 + 1; w = 97; }
    size_t e = ((size_t)(b * PH + h) * PW + w) * 256 + oct * 8;
    *(uint4*)(t + e) = make_uint4(0u, 0u, 0u, 0u);
}

// ---- pack weights fp32 [co][ci][3][3] -> bf16 [cc][k9][c'][ci32] ----
template<bool PERM>
__global__ __launch_bounds__(256)
void pack_w_k(const float* __restrict__ w, unsigned short* __restrict__ wp) {
    int idx = blockIdx.x * 256 + threadIdx.x;      // 589824
    int ci_l = idx & 31;
    int c    = (idx >> 5) & 255;
    int v    = idx >> 13;          // 0..71
    int k9   = v % 9;
    int cc   = v / 9;
    int co;
    if (PERM) {
        co = (c < 86) ? c * 3 : (c < 171) ? (c - 86) * 3 + 1 : (c - 171) * 3 + 2;
    } else {
        co = c;
    }
    float val = w[((size_t)co * 256 + cc * 32 + ci_l) * 9 + k9];
    wp[idx] = f2bf(val);
}

// ---- x fp32 NCHW -> padded channels-last bf16 (interior only) ----
__global__ __launch_bounds__(256)
void transform_x_k(const float* __restrict__ x, unsigned short* __restrict__ xp) {
    __shared__ float s[32 * 33];
    const int t = threadIdx.x;
    const int col0 = blockIdx.x * 32;
    const int row  = blockIdx.y;
    const int z = blockIdx.z;
    const int b = z >> 3;
    const int ci0 = (z & 7) * 32;

    #pragma unroll
    for (int i = 0; i < 4; ++i) {
        int ci = i * 8 + (t >> 5);
        int px = t & 31;
        s[ci * 33 + px] = x[((size_t)(b * Cn + ci0 + ci)) * HW + row * Wn + col0 + px];
    }
    __syncthreads();
    const int px = t >> 3;
    const int c4 = (t & 7) * 4;
    ushort4 o;
    o.x = f2bf(s[(c4 + 0) * 33 + px]);
    o.y = f2bf(s[(c4 + 1) * 33 + px]);
    o.z = f2bf(s[(c4 + 2) * 33 + px]);
    o.w = f2bf(s[(c4 + 3) * 33 + px]);
    size_t e = ((size_t)(b * PH + row + 1) * PW + (col0 + px + 1)) * 256 + ci0 + c4;
    *(ushort4*)(xp + e) = o;
}

// ---- MFMA conv3x3: weights direct global->reg, x via LDS ----
// 256 threads (4 waves). Block: 64 co x (12 rows x 32 cols).
// Wave wv owns rows wv*3..wv*3+2: m=4 co-frags, n=6 px-frags (16x16x32).
// 72 regions s = c*9+k9, ONE barrier per chunk (at k9=8). Per region:
//   issue 4 global A-loads (region s+1) -> Areg[(s+1)&1]
//   issue 1 x gl_lds slice (k9<8) into s_x[(c+1)&1]
//   6 ds_read B; lgkm(0); 24 MFMA on Areg[s&1]; vmcnt(1) [k9=8: vmcnt(0)+bar]
// x staging via PRE-SWIZZLED SOURCE (rule #21), involution
// phys16Bslot = logical ^ ((logical>>3)&3); reads apply the same XOR.
template<int MODE>
__global__ __launch_bounds__(256, 2)
void conv_k(const unsigned short* __restrict__ in_cl,
            const unsigned short* __restrict__ wp,
            const float* __restrict__ prelu_w,
            const float* __restrict__ xres,
            void* __restrict__ outp)
{
    __shared__ unsigned short s_x[2][2048 * 8];   // 2 x 32768 B [px(14x34)][ci32]

    const int tid = threadIdx.x;
    const int bid = blockIdx.x;
    // XCD-chunked bijective swizzle (1536 = 8 * 192); co-group fastest.
    const int wg = (bid & 7) * 192 + (bid >> 3);
    const int co_base = (wg & 3) * 64;
    const int t2 = wg >> 2;            // 0..383
    const int tile = t2 % 24;
    const int b = t2 / 24;
    const int R0 = (tile / 3) * 12;    // padded-coord halo base row
    const int C0 = (tile % 3) * 32;

    const int lane = tid & 63;
    const int wv = tid >> 6;
    const int l15 = lane & 15;
    const int qq = lane >> 4;

    const unsigned short* img = in_cl + (size_t)b * PH * PW * 256;

    // ---- x staging map: 8 slices, dest linear (i*256+tid), source pre-swizzled ----
    // logical slots 0..1903 (476 px * 4 parts); dests 1904..2047 clamp-dup.
    int xg[8];
    #pragma unroll
    for (int i = 0; i < 8; ++i) {
        int slot = i * 256 + tid;
        int lsl = slot ^ ((slot >> 3) & 3);    // involution, preserves slot>>3
        if (lsl > 1903) lsl = 1903;
        int p = lsl >> 2;
        int pr = p / 34, pc = p - pr * 34;
        xg[i] = ((R0 + pr) * PW + (C0 + pc)) * 256 + (lsl & 3) * 8;
    }
    // ---- A fragment global offsets (ushorts): frag m of a slice ----
    int aoff[4];
    #pragma unroll
    for (int m = 0; m < 4; ++m)
        aoff[m] = (co_base + m * 16 + l15) * 32 + qq * 8;

    f32x4 acc[4][6];
    #pragma unroll
    for (int m = 0; m < 4; ++m)
        #pragma unroll
        for (int n = 0; n < 6; ++n) acc[m][n] = 0.f;

    bf16x8 A0[4], A1[4];

    // ---- prologue: x chunk0 (8 slices), A(region 0) -> A0 ----
    #pragma unroll
    for (int i = 0; i < 8; ++i)
        lds_load16(&s_x[0][(size_t)(i * 256 + tid) * 8], img + xg[i]);
    #pragma unroll
    for (int m = 0; m < 4; ++m)
        A0[m] = *(const bf16x8*)(wp + aoff[m]);
    MEMFENCE(); SB();
    asm volatile("s_waitcnt vmcnt(0)" ::: "memory");
    SB();
    __builtin_amdgcn_s_barrier();
    SB();

// One region. K9 static; AUSE/ALD statically alternate (s parity).
#define REGION(K9, AUSE, ALD) {                                                   \
    /* A-loads for region s+1 (first into VMEM FIFO) */                           \
    _Pragma("unroll")                                                             \
    for (int m = 0; m < 4; ++m)                                                   \
        ALD[m] = *(const bf16x8*)(wpc + (K9 + 1) * 8192 + aoff[m]);               \
    MEMFENCE(); SB();                                                             \
    /* x slice (chunk c+1, other buffer) */                                       \
    if ((K9) < 8)                                                                 \
        lds_load16(&sxn[(size_t)((K9) * 256 + tid) * 8], img + xg[(K9)] + cn32);  \
    MEMFENCE(); SB();                                                             \
    /* B fragment reads */                                                        \
    bf16x8 bf[6];                                                                 \
    {                                                                             \
        const int kh_ = (K9) / 3, kw_ = (K9) - 3 * ((K9) / 3);                    \
        _Pragma("unroll")                                                         \
        for (int n = 0; n < 6; ++n) {                                             \
            const int P_ = (wv * 3 + (n >> 1) + kh_) * 34 + (n & 1) * 16 + l15 + kw_; \
            bf[n] = *(const bf16x8*)&sxc[P_ * 32 + ((qq ^ ((P_ >> 1) & 3)) << 3)]; \
        }                                                                         \
    }                                                                             \
    asm volatile("s_waitcnt lgkmcnt(0)" ::: "memory");                            \
    SB();                                                                         \
    __builtin_amdgcn_s_setprio(1);                                                \
    _Pragma("unroll")                                                             \
    for (int n = 0; n < 6; ++n)                                                   \
        _Pragma("unroll")                                                         \
        for (int m = 0; m < 4; ++m)                                               \
            acc[m][n] = __builtin_amdgcn_mfma_f32_16x16x32_bf16(AUSE[m], bf[n], acc[m][n], 0, 0, 0); \
    __builtin_amdgcn_s_setprio(0);                                                \
    SB();                                                                         \
    if ((K9) < 8) { asm volatile("s_waitcnt vmcnt(1)" ::: "memory"); }            \
    else          { asm volatile("s_waitcnt vmcnt(0)" ::: "memory"); }            \
    SB();                                                                         \
    if ((K9) == 8) { __builtin_amdgcn_s_barrier(); SB(); }                        \
}

// Chunk body: 9 regions; PAR = c parity (s parity = (c+k9)&1).
#define CHUNK_EVEN() { \
    REGION(0, A0, A1) REGION(1, A1, A0) REGION(2, A0, A1)                         \
    REGION(3, A1, A0) REGION(4, A0, A1) REGION(5, A1, A0)                         \
    REGION(6, A0, A1) REGION(7, A1, A0) REGION(8, A0, A1) }
#define CHUNK_ODD() { \
    REGION(0, A1, A0) REGION(1, A0, A1) REGION(2, A1, A0)                         \
    REGION(3, A0, A1) REGION(4, A1, A0) REGION(5, A0, A1)                         \
    REGION(6, A1, A0) REGION(7, A0, A1) REGION(8, A1, A0) }

    for (int c2 = 0; c2 < 4; ++c2) {
        {
            const int c = 2 * c2;
            const unsigned short* wpc = wp + (size_t)c * 73728;
            const unsigned short* sxc = s_x[0];
            unsigned short* sxn = s_x[1];
            const int cn32 = ((c + 1) & 7) * 32;
            CHUNK_EVEN()
        }
        {
            const int c = 2 * c2 + 1;
            const unsigned short* wpc = wp + (size_t)c * 73728;
            const unsigned short* sxc = s_x[1];
            unsigned short* sxn = s_x[0];
            const int cn32 = ((c + 1) & 7) * 32;
            CHUNK_ODD()
        }
    }
#undef REGION
#undef CHUNK_EVEN
#undef CHUNK_ODD

    // ---- epilogue (n-outer, m-inner for write combining) ----
    if constexpr (MODE == 0) {
        const float pw = prelu_w[0];
        unsigned short* aout = (unsigned short*)outp;
        #pragma unroll
        for (int n = 0; n < 6; ++n) {
            const int row_p = wv * 3 + (n >> 1);
            const int col_p = (n & 1) * 16 + l15;
            size_t pix = ((size_t)(b * PH + R0 + row_p + 1)) * PW + (C0 + col_p + 1);
            #pragma unroll
            for (int m = 0; m < 4; ++m) {
                const int cb = co_base + m * 16 + qq * 4;
                float r[4];
                #pragma unroll
                for (int j = 0; j < 4; ++j) {
                    const int ch = cb + j;
                    float s = acc[m][n][j];
                    if (ch < 86)        r[j] = s >= 0.f ? s : pw * s;
                    else if (ch < 171)  r[j] = fmaxf(s, 0.f);
                    else {
                        float e = __expf(2.f * s);
                        r[j] = 1.f - 2.f / (e + 1.f);
                    }
                }
                ushort4 o;
                o.x = f2bf(r[0]); o.y = f2bf(r[1]); o.z = f2bf(r[2]); o.w = f2bf(r[3]);
                *(ushort4*)(aout + pix * 256 + cb) = o;
            }
        }
    } else {
        float* fout = (float*)outp;
        #pragma unroll
        for (int n = 0; n < 6; ++n) {
            const int row_p = wv * 3 + (n >> 1);
            const int col_p = (n & 1) * 16 + l15;
            #pragma unroll
            for (int m = 0; m < 4; ++m) {
                const int cb = co_base + m * 16 + qq * 4;
                size_t base = ((size_t)(b * Cn + cb)) * HW + (size_t)(R0 + row_p) * Wn + (C0 + col_p);
                #pragma unroll
                for (int j = 0; j < 4; ++j)
                    fout[base + (size_t)j * HW] = acc[m][n][j] * 0.1f + xres[base + (size_t)j * HW];
            }
        }
    }
}

extern "C" void kernel_launch(void* const* d_in, const int* in_sizes, int n_in,
                              void* d_out, int out_size, void* d_ws, size_t ws_size,
                              hipStream_t stream) {
    const float* x  = (const float*)d_in[0];
    const float* w2 = (const float*)d_in[1];
    const float* w3 = (const float*)d_in[2];
    const float* pw = (const float*)d_in[3];
    float* out = (float*)d_out;
    char* ws = (char*)d_ws;

    // ws layout: a_cl (78,675,968 B) | wp2 (1,179,648 B) | wp3 (1,179,648 B) | spare
    // (the dead last-region A-prefetch reads 8KB past wp2/wp3 - lands in
    //  wp3/spare, harmless; ws proven >= 155 MB in R1)
    unsigned short* a_cl = (unsigned short*)ws;
    unsigned short* wp2  = (unsigned short*)(ws + 78675968);
    unsigned short* wp3  = (unsigned short*)(ws + 78675968 + 1179648);
    // x_pad aliases d_out (78.7 MB <= 151 MB); dead before conv<1> writes d_out.
    unsigned short* x_pad = (unsigned short*)d_out;

    zero_border_k<<<776, 256, 0, stream>>>(x_pad);
    zero_border_k<<<776, 256, 0, stream>>>(a_cl);
    pack_w_k<true ><<<2304, 256, 0, stream>>>(w2, wp2);
    pack_w_k<false><<<2304, 256, 0, stream>>>(w3, wp3);
    transform_x_k<<<dim3(3, 96, 128), 256, 0, stream>>>(x, x_pad);

    conv_k<0><<<1536, 256, 0, stream>>>(x_pad, wp2, pw, nullptr, (void*)a_cl);
    conv_k<1><<<1536, 256, 0, stream>>>(a_cl, wp3, nullptr, x, (void*)out);
}